// Round 10
// baseline (7378.696 us; speedup 1.0000x reference)
//
#include <hip/hip_runtime.h>
#include <stdint.h>

typedef _Float16 f16;
typedef _Float16 f16x4 __attribute__((ext_vector_type(4)));
typedef _Float16 f16x8 __attribute__((ext_vector_type(8)));
typedef float f32x4 __attribute__((ext_vector_type(4)));

#define SEQ 512
#define NB  200
#define HD  256
#define GD  768
#define BW  16
#define NBLK 13                    // ceil(200/16)
#define GI_TSTRIDE (NBLK*12288)    // halves per timestep = 159744
#define LOG2E 1.44269504f
// gru LDS map (bytes): [0,98304) weight tiles [w][s][kk][lane*16]
//                      [98304,114688) h dbuf 2x8192
//                      [114688,163840) gi dbuf 2x24576   == 160 KiB exactly
#define SMH 98304
#define SMG 114688

__device__ __forceinline__ f32x4 mfma16(f16x8 a, f16x8 b, f32x4 c){
  return __builtin_amdgcn_mfma_f32_16x16x32_f16(a, b, c, 0, 0, 0);
}

// ---------------- fp32 -> fp16 convert ----------------
__global__ void cvt_f32_f16(const float* __restrict__ src, f16* __restrict__ dst, int n4){
  int i = blockIdx.x * blockDim.x + threadIdx.x;
  int stride = gridDim.x * blockDim.x;
  for (; i < n4; i += stride){
    float4 v = ((const float4*)src)[i];
    f16x4 o = { (f16)v.x, (f16)v.y, (f16)v.z, (f16)v.w };
    ((f16x4*)dst)[i] = o;
  }
}

// ---------------- GEMM: C[m][n] = sum_k A[m][k]*B[n][k] (both K-major) -------
// MODE 0: fp16 out into PERMUTED GI layout for the 4-wave gru reader.
//   Per (t,bblk): 24KB region = 24 1KB chunks, wave w owns chunks [6w,6w+6).
//   g -> q=g>>8, j'=g&255, ww=j'>>6, jj=j'&63, t4=jj>>4, lg=(jj>>2)&3, rr=jj&3,
//   lane = lg*16 + (b&15).
//   q<2 (r,z): half = region + (ww*6+t4)*512 + lane*8 + q*4 + rr
//   q==2 (n):  half = region + (ww*6+4+(t4>>1))*512 + lane*8 + (t4&1)*4 + rr
//   bias1[g] (+bias2[g] for g<512: b_hh r,z folded in exactly).
// MODE 1: fp32 partials out[(z*512+row)*N+col].  grid (M/128, N/128, splits)
template<int MODE>
__global__ __launch_bounds__(256, 2)
void gemm_bt(const f16* __restrict__ A, const f16* __restrict__ B,
             f16* __restrict__ Cb, float* __restrict__ Cf,
             const float* __restrict__ bias1, const float* __restrict__ bias2,
             int K, int N, int klen)
{
  const int l  = threadIdx.x & 63;
  const int w  = threadIdx.x >> 6;
  const int lr = l & 15, lg = l >> 4;
  const int Mb = blockIdx.x * 128 + (w >> 1) * 64;
  const int Nb = blockIdx.y * 128 + (w & 1) * 64;
  const int kb = blockIdx.z * klen;

  const f16* Ap = A + (size_t)(Mb + lr) * K + kb + lg * 8;
  const f16* Bp = B + (size_t)(Nb + lr) * K + kb + lg * 8;

  f32x4 acc[4][4];
  #pragma unroll
  for (int i = 0; i < 4; ++i)
    #pragma unroll
    for (int j = 0; j < 4; ++j)
      acc[i][j] = (f32x4){0.f, 0.f, 0.f, 0.f};

  for (int k = 0; k < klen; k += 32){
    f16x8 af[4], bfr[4];
    #pragma unroll
    for (int i = 0; i < 4; ++i){
      af[i]  = *(const f16x8*)(Ap + (size_t)i * 16 * K + k);
      bfr[i] = *(const f16x8*)(Bp + (size_t)i * 16 * K + k);
    }
    #pragma unroll
    for (int i = 0; i < 4; ++i)
      #pragma unroll
      for (int j = 0; j < 4; ++j)
        acc[i][j] = mfma16(af[i], bfr[j], acc[i][j]);
  }

  if (MODE == 0){
    float bv[4];
    #pragma unroll
    for (int j = 0; j < 4; ++j){
      int g = Nb + j*16 + lr;
      bv[j] = bias1[g] + (g < 512 ? bias2[g] : 0.f);
    }
    #pragma unroll
    for (int i = 0; i < 4; ++i)
      #pragma unroll
      for (int r = 0; r < 4; ++r){
        int row = Mb + i*16 + lg*4 + r;
        int t = (int)(((uint64_t)(uint32_t)row * 167773u) >> 25);  // row/200 exact
        int b = row - t*200;
        int bblk = b >> 4, blr = b & 15;
        size_t region = ((size_t)t*NBLK + bblk) * 12288;
        #pragma unroll
        for (int j = 0; j < 4; ++j){
          int g = Nb + j*16 + lr;
          int q = g >> 8, jp = g & 255;
          int ww = jp >> 6, jj = jp & 63;
          int t4 = jj >> 4, lg2 = (jj >> 2) & 3, rr = jj & 3;
          int lane = lg2*16 + blr;
          size_t idx;
          if (q < 2) idx = region + (size_t)(ww*6 + t4)*512 + lane*8 + q*4 + rr;
          else       idx = region + (size_t)(ww*6 + 4 + (t4>>1))*512 + lane*8 + (t4&1)*4 + rr;
          Cb[idx] = (f16)(acc[i][j][r] + bv[j]);
        }
      }
  } else {
    #pragma unroll
    for (int i = 0; i < 4; ++i)
      #pragma unroll
      for (int j = 0; j < 4; ++j)
        #pragma unroll
        for (int r = 0; r < 4; ++r){
          int row = Mb + i*16 + lg*4 + r;
          int col = Nb + j*16 + lr;
          Cf[((size_t)blockIdx.z * 512 + row) * N + col] = acc[i][j][r];
        }
  }
}

// ---------------- persistent GRU layer: 13 blocks x 16 batch rows ------------
// 256 threads = 4 waves = 1/SIMD, waves_per_eu(1,1) -> 256-VGPR budget (the
// ONLY config that measurably granted 256: round 5). Wave w owns hidden
// [64w,64w+64) = 12 gate tiles. Weight bytes split 3 ways so 256 regs suffice:
//   3 tiles pinned in regs (96 VGPR), 3 tiles LDS-resident (96KB staged once),
//   6 tiles streamed from L2 each step (192KB/block/step — HALF of round 9's
//   384KB, which sat exactly at the per-CU L2 port ~140GB/s).
// h dbuf in LDS (swizzle c(b)=(b^(b>>2))&3); h_old in regs; gi prefetched one
// step ahead via global_load_lds (6 chunks/wave).
__global__
__attribute__((amdgpu_flat_work_group_size(256, 256), amdgpu_waves_per_eu(1, 1)))
void gru_layer(const f16* __restrict__ whh, const float* __restrict__ bhh,
               const f16* __restrict__ gi, f16* __restrict__ hs)
{
  __shared__ __align__(16) unsigned char sm[163840];   // 160 KiB exactly
  const int tid = threadIdx.x;
  const int w  = tid >> 6, l = tid & 63;
  const int lr = l & 15, lg = l >> 4;
  const int b0 = blockIdx.x * BW;
  const bool bval = (b0 + lr) < NB;

  ((int4*)(sm + SMH))[tid]       = make_int4(0,0,0,0);   // zero h buf0 (8KB)
  ((int4*)(sm + SMH))[tid + 256] = make_int4(0,0,0,0);

  const f16* glane = gi + (size_t)blockIdx.x*12288 + w*3072 + l*8;
#define DMA_GI(P) do { \
    _Pragma("unroll") \
    for (int c = 0; c < 6; ++c) \
      __builtin_amdgcn_global_load_lds( \
          (const __attribute__((address_space(1))) void*)(glane + c*512), \
          (__attribute__((address_space(3))) void*)(sm + SMG + (P)*24576 + w*6144 + c*1024), \
          16, 0, 0); \
  } while(0)

  DMA_GI(0);   // t=0 prefetch

  // stage 3 LDS-resident weight tiles: (q,t4) = (0,3),(1,0),(1,1)
  {
    const int SQ[3] = {0,1,1}, ST[3] = {3,0,1};
    #pragma unroll
    for (int s = 0; s < 3; ++s)
      #pragma unroll
      for (int kk = 0; kk < 8; ++kk){
        f16x8 v = *(const f16x8*)(whh + (size_t)(SQ[s]*256 + w*64 + ST[s]*16 + lr)*256 + kk*32 + lg*8);
        *(f16x8*)(sm + w*24576 + s*8192 + kk*1024 + l*16) = v;
      }
  }

  // pinned register tiles: (q=0, t4=0..2)
  f16x8 wR[3][8];
  #pragma unroll
  for (int t = 0; t < 3; ++t)
    #pragma unroll
    for (int kk = 0; kk < 8; ++kk)
      wR[t][kk] = *(const f16x8*)(whh + (size_t)(w*64 + t*16 + lr)*256 + kk*32 + lg*8);
  #pragma unroll
  for (int t = 0; t < 3; ++t)
    #pragma unroll
    for (int kk = 0; kk < 8; ++kk)
      asm volatile("" : "+v"(wR[t][kk]));

  // streamed tile base pointers: (q,t4) = (1,2),(1,3),(2,0),(2,1),(2,2),(2,3)
  const int MQ[6] = {1,1,2,2,2,2}, MT[6] = {2,3,0,1,2,3};
  const f16* wS[6];
  #pragma unroll
  for (int m = 0; m < 6; ++m)
    wS[m] = whh + (size_t)(MQ[m]*256 + w*64 + MT[m]*16 + lr)*256 + lg*8;

  // n-gate bias per t4 (acc init)
  f32x4 bn4[4];
  #pragma unroll
  for (int t4 = 0; t4 < 4; ++t4){
    float4 bv = *(const float4*)(bhh + 512 + w*64 + t4*16 + lg*4);
    bn4[t4] = (f32x4){bv.x, bv.y, bv.z, bv.w};
  }

  // LDS addressing. h element (k,b) at byte SMH + (k>>5)*1024 + b*64 +
  //   (((k&31)*2) ^ (c(b)<<4)),  c(b) = (b ^ (b>>2)) & 3
  const int cswz = ((lr ^ (lr >> 2)) & 3) << 4;
  const int hrd = SMH + lr*64 + ((lg*16) ^ cswz);   // + P*8192 + kk*1024
  const int gib = SMG + w*6144 + l*16;              // + P*24576 + chunk*1024

  f16* hp = hs + (size_t)(b0 + lr)*HD + w*64 + lg*4;
  f16x4 hv0p = (f16x4){(f16)0.f,(f16)0.f,(f16)0.f,(f16)0.f};
  f16x4 hv1p = hv0p, hv2p = hv0p, hv3p = hv0p;

  asm volatile("s_waitcnt vmcnt(0)" ::: "memory");  // drain prologue
  __syncthreads();

#define GATE(P, T4, AR, AZ, AN, HVP) do { \
    f16x8 rz = *(const f16x8*)(sm + (P)*24576 + gib + (T4)*1024); \
    f16x4 nn = *(const f16x4*)(sm + (P)*24576 + gib + (4+((T4)>>1))*1024 + ((T4)&1)*8); \
    f16x4 hv; \
    _Pragma("unroll") \
    for (int r = 0; r < 4; ++r){ \
      float rg = __builtin_amdgcn_rcpf(1.f + __builtin_amdgcn_exp2f(-LOG2E*((float)rz[r] + AR[r]))); \
      float zg = __builtin_amdgcn_rcpf(1.f + __builtin_amdgcn_exp2f(-LOG2E*((float)rz[4+r] + AZ[r]))); \
      float aa = (float)nn[r] + rg*AN[r]; \
      float ng = 2.f*__builtin_amdgcn_rcpf(1.f + __builtin_amdgcn_exp2f(-2.f*LOG2E*aa)) - 1.f; \
      float h  = ng + zg*((float)HVP[r] - ng); \
      hv[r] = (f16)h; \
    } \
    HVP = hv; \
    *(f16x4*)(sm + SMH + ((P)^1)*8192 + (w*2 + ((T4)>>1))*1024 + lr*64 \
              + ((((T4)&1)*32 | (lg*8)) ^ cswz)) = hv; \
    if (bval) *(f16x4*)(hp + (T4)*16) = hv; \
  } while(0)

#define GRUSTEP(P) do { \
    asm volatile("s_waitcnt vmcnt(0)" ::: "memory"); /* gi DMAs landed */ \
    f32x4 aR0={0.f,0.f,0.f,0.f}, aR1=aR0, aR2=aR0, aR3=aR0; \
    f32x4 aZ0=aR0, aZ1=aR0, aZ2=aR0, aZ3=aR0; \
    f32x4 aN0=bn4[0], aN1=bn4[1], aN2=bn4[2], aN3=bn4[3]; \
    glane += GI_TSTRIDE; \
    DMA_GI((P)^1); \
    _Pragma("unroll") \
    for (int kk = 0; kk < 8; ++kk){ \
      f16x8 hf = *(const f16x8*)(sm + (P)*8192 + kk*1024 + hrd); \
      aR0 = mfma16(wR[0][kk], hf, aR0); \
      aR1 = mfma16(wR[1][kk], hf, aR1); \
      aR2 = mfma16(wR[2][kk], hf, aR2); \
      f16x8 l0 = *(const f16x8*)(sm + w*24576 + 0*8192 + kk*1024 + l*16); \
      f16x8 l1 = *(const f16x8*)(sm + w*24576 + 1*8192 + kk*1024 + l*16); \
      f16x8 l2 = *(const f16x8*)(sm + w*24576 + 2*8192 + kk*1024 + l*16); \
      aR3 = mfma16(l0, hf, aR3); \
      aZ0 = mfma16(l1, hf, aZ0); \
      aZ1 = mfma16(l2, hf, aZ1); \
      f16x8 s0 = *(const f16x8*)(wS[0] + kk*32); \
      f16x8 s1 = *(const f16x8*)(wS[1] + kk*32); \
      f16x8 s2 = *(const f16x8*)(wS[2] + kk*32); \
      f16x8 s3 = *(const f16x8*)(wS[3] + kk*32); \
      f16x8 s4 = *(const f16x8*)(wS[4] + kk*32); \
      f16x8 s5 = *(const f16x8*)(wS[5] + kk*32); \
      aZ2 = mfma16(s0, hf, aZ2); \
      aZ3 = mfma16(s1, hf, aZ3); \
      aN0 = mfma16(s2, hf, aN0); \
      aN1 = mfma16(s3, hf, aN1); \
      aN2 = mfma16(s4, hf, aN2); \
      aN3 = mfma16(s5, hf, aN3); \
    } \
    GATE(P, 0, aR0, aZ0, aN0, hv0p); \
    GATE(P, 1, aR1, aZ1, aN1, hv1p); \
    GATE(P, 2, aR2, aZ2, aN2, hv2p); \
    GATE(P, 3, aR3, aZ3, aN3, hv3p); \
    hp += (size_t)NB*HD; \
    asm volatile("s_waitcnt lgkmcnt(0)" ::: "memory"); \
    __builtin_amdgcn_sched_barrier(0); \
    __builtin_amdgcn_s_barrier(); \
    __builtin_amdgcn_sched_barrier(0); \
  } while(0)

  for (int th = 0; th < SEQ/2; ++th){
    GRUSTEP(0);
    GRUSTEP(1);
  }
#undef GRUSTEP
#undef GATE
#undef DMA_GI
}

// ---------------- LayerNorm(hidden) + ReLU, in place on fp16 [rows][256] -----
__global__ __launch_bounds__(256)
void ln_relu(f16* __restrict__ hs, const float* __restrict__ lnw,
             const float* __restrict__ lnb)
{
  const int tid = threadIdx.x;
  const int wv = tid >> 6;           // 4 waves/block
  const int lane = tid & 63;
  const int half = lane >> 5;        // row within pair
  const int c0 = (lane & 31) * 8;
  float gw[8], gb[8];
  #pragma unroll
  for (int r = 0; r < 8; ++r){ gw[r] = lnw[c0 + r]; gb[r] = lnb[c0 + r]; }
  const int npairs = SEQ * NB / 2;   // 51200
  for (int pair = blockIdx.x * 4 + wv; pair < npairs; pair += gridDim.x * 4){
    f16* p = hs + (size_t)(pair*2 + half) * HD + c0;
    f16x8 v = *(const f16x8*)p;
    float f[8], s = 0.f, q = 0.f;
    #pragma unroll
    for (int r = 0; r < 8; ++r){ f[r] = (float)v[r]; s += f[r]; q += f[r]*f[r]; }
    #pragma unroll
    for (int off = 16; off; off >>= 1){
      s += __shfl_xor(s, off);
      q += __shfl_xor(q, off);
    }
    float mu = s * (1.f / HD);
    float var = q * (1.f / HD) - mu * mu;
    float rs = rsqrtf(var + 1e-5f);
    f16x8 o;
    #pragma unroll
    for (int r = 0; r < 8; ++r){
      float y = (f[r] - mu) * rs * gw[r] + gb[r];
      o[r] = (f16)fmaxf(y, 0.f);
    }
    *(f16x8*)p = o;
  }
}

// ---------------- BatchNorm over axis0 (batch stats) + ReLU ------------------
__global__ __launch_bounds__(512)
void bn_relu(const float* __restrict__ part, const float* __restrict__ g,
             const float* __restrict__ b, float* __restrict__ z)
{
  __shared__ float lds[16];
  const int o = blockIdx.x, s = threadIdx.x, w = s >> 6;
  float y = 0.f;
  #pragma unroll
  for (int p = 0; p < 8; ++p) y += part[((size_t)p * 512 + o) * 512 + s];
  float su = y, q = y * y;
  #pragma unroll
  for (int off = 32; off; off >>= 1){
    su += __shfl_down(su, off);
    q  += __shfl_down(q, off);
  }
  if ((s & 63) == 0){ lds[w] = su; lds[8 + w] = q; }
  __syncthreads();
  float S = 0.f, Q = 0.f;
  #pragma unroll
  for (int i = 0; i < 8; ++i){ S += lds[i]; Q += lds[8 + i]; }
  float mu = S * (1.f / 512.f);
  float var = Q * (1.f / 512.f) - mu * mu;
  float zz = fmaxf((y - mu) * rsqrtf(var + 1e-5f) * g[o] + b[o], 0.f);
  z[(size_t)o * 512 + s] = zz;   // stored transposed [o][s]
}

// ---------------- fc3: out[s][c] = sum_o z[o][s]*w[c][o] + b[c] --------------
__global__ __launch_bounds__(256)
void fc3_k(const float* __restrict__ z, const float* __restrict__ w,
           const float* __restrict__ b, float* __restrict__ out)
{
  __shared__ float lds[12];
  const int s = blockIdx.x, tid = threadIdx.x, wv = tid >> 6;
  float a0 = 0.f, a1 = 0.f, a2 = 0.f;
  for (int o = tid; o < 512; o += 256){
    float zz = z[(size_t)o * 512 + s];
    a0 += zz * w[o];
    a1 += zz * w[512 + o];
    a2 += zz * w[1024 + o];
  }
  #pragma unroll
  for (int off = 32; off; off >>= 1){
    a0 += __shfl_down(a0, off);
    a1 += __shfl_down(a1, off);
    a2 += __shfl_down(a2, off);
  }
  if ((tid & 63) == 0){ lds[wv] = a0; lds[4 + wv] = a1; lds[8 + wv] = a2; }
  __syncthreads();
  if (tid == 0){
    out[s*3 + 0] = lds[0] + lds[1] + lds[2]  + lds[3]  + b[0];
    out[s*3 + 1] = lds[4] + lds[5] + lds[6]  + lds[7]  + b[1];
    out[s*3 + 2] = lds[8] + lds[9] + lds[10] + lds[11] + b[2];
  }
}

extern "C" void kernel_launch(void* const* d_in, const int* in_sizes, int n_in,
                              void* d_out, int out_size, void* d_ws, size_t ws_size,
                              hipStream_t stream)
{
  (void)in_sizes; (void)n_in; (void)out_size; (void)ws_size;
  const float* x    = (const float*)d_in[0];
  const float* wih0 = (const float*)d_in[1];
  const float* whh0 = (const float*)d_in[2];
  const float* bih0 = (const float*)d_in[3];
  const float* bhh0 = (const float*)d_in[4];
  const float* wih1 = (const float*)d_in[5];
  const float* whh1 = (const float*)d_in[6];
  const float* bih1 = (const float*)d_in[7];
  const float* bhh1 = (const float*)d_in[8];
  const float* lnw  = (const float*)d_in[9];
  const float* lnb  = (const float*)d_in[10];
  const float* fc2w = (const float*)d_in[11];
  // d_in[12] = fc2_b skipped: BN mean-centering cancels constant column bias.
  const float* bng  = (const float*)d_in[13];
  const float* bnb  = (const float*)d_in[14];
  const float* fc3w = (const float*)d_in[15];
  const float* fc3b = (const float*)d_in[16];
  float* out = (float*)d_out;

  char* ws = (char*)d_ws;
  size_t off = 0;
  auto alloc = [&](size_t bytes) -> void* {
    void* p = ws + off; off += (bytes + 255) & ~(size_t)255; return p;
  };
  f16* GI     = (f16*)alloc((size_t)SEQ*GI_TSTRIDE*2);  // 163.6 MB (permuted layout)
  f16* X16    = (f16*)alloc((size_t)SEQ*NB*64*2);       // 13.1 MB
  f16* WI0    = (f16*)alloc((size_t)768*64*2);
  f16* WH0    = (f16*)alloc((size_t)768*256*2);
  f16* WI1    = (f16*)alloc((size_t)768*256*2);
  f16* WH1    = (f16*)alloc((size_t)768*256*2);
  f16* HS0    = (f16*)alloc((size_t)SEQ*NB*256*2);      // 52.4 MB
  f16* HS1    = (f16*)alloc((size_t)SEQ*NB*256*2);      // 52.4 MB
  float* PART = (float*)alloc((size_t)8*512*512*4);     // 8.4 MB
  float* Z    = (float*)alloc((size_t)512*512*4);       // 1 MB (total ~292 MB)
  f16* FC2W   = GI;   // aliased: GI dead after gru1, FC2W converted after gru1

  cvt_f32_f16<<<2048,256,0,stream>>>(x,    X16,  SEQ*NB*64/4);
  cvt_f32_f16<<<64,  256,0,stream>>>(wih0, WI0,  768*64/4);
  cvt_f32_f16<<<192, 256,0,stream>>>(whh0, WH0,  768*256/4);
  cvt_f32_f16<<<192, 256,0,stream>>>(wih1, WI1,  768*256/4);
  cvt_f32_f16<<<192, 256,0,stream>>>(whh1, WH1,  768*256/4);

  dim3 g0(800, 6, 1);
  // gi0 = x @ w_ih0^T + b_ih0 (+ b_hh0 for r,z gates), permuted layout
  gemm_bt<0><<<g0, 256, 0, stream>>>(X16, WI0, GI, nullptr, bih0, bhh0, 64, GD, 64);
  gru_layer<<<NBLK, 256, 0, stream>>>(WH0, bhh0, GI, HS0);
  gemm_bt<0><<<g0, 256, 0, stream>>>(HS0, WI1, GI, nullptr, bih1, bhh1, 256, GD, 256);
  gru_layer<<<NBLK, 256, 0, stream>>>(WH1, bhh1, GI, HS1);
  // LayerNorm + ReLU in place -> hflat (fp16, layout already (512, 51200))
  ln_relu<<<3200, 256, 0, stream>>>(HS1, lnw, lnb);
  // fc2 weights converted now (GI dead), into GI-aliased buffer
  cvt_f32_f16<<<4096,256,0,stream>>>(fc2w, FC2W, 512*51200/4);
  dim3 g2(4, 4, 8);
  gemm_bt<1><<<g2, 256, 0, stream>>>(FC2W, HS1, nullptr, PART, nullptr, nullptr, 51200, 512, 6400);
  bn_relu<<<512, 512, 0, stream>>>(PART, bng, bnb, Z);
  fc3_k<<<512, 256, 0, stream>>>(Z, fc3w, fc3b, out);
}

// Round 11
// 4819.183 us; speedup vs baseline: 1.5311x; 1.5311x over previous
//
#include <hip/hip_runtime.h>
#include <stdint.h>

typedef _Float16 f16;
typedef _Float16 f16x4 __attribute__((ext_vector_type(4)));
typedef _Float16 f16x8 __attribute__((ext_vector_type(8)));
typedef float f32x4 __attribute__((ext_vector_type(4)));

#define SEQ 512
#define NB  200
#define HD  256
#define GD  768
#define BW  16
#define NBLK 13           // ceil(200/16)
#define NBP 208           // padded batch for GI layout
#define GI_TSTRIDE (3*32*NBP*8)   // halves per timestep = 159744
#define LOG2E 1.44269504f
// gru LDS map (bytes): [0,65536) weight tiles (wave w: [w*8192,(w+1)*8192))
//                      [65536,81920) h dbuf 2x8192
//                      [81920,106496) gi single buffer 3x8192
#define HB  65536
#define GIB 81920

__device__ __forceinline__ f32x4 mfma16(f16x8 a, f16x8 b, f32x4 c){
  return __builtin_amdgcn_mfma_f32_16x16x32_f16(a, b, c, 0, 0, 0);
}

// ---------------- fp32 -> fp16 convert ----------------
__global__ void cvt_f32_f16(const float* __restrict__ src, f16* __restrict__ dst, int n4){
  int i = blockIdx.x * blockDim.x + threadIdx.x;
  int stride = gridDim.x * blockDim.x;
  for (; i < n4; i += stride){
    float4 v = ((const float4*)src)[i];
    f16x4 o = { (f16)v.x, (f16)v.y, (f16)v.z, (f16)v.w };
    ((f16x4*)dst)[i] = o;
  }
}

// ---------------- GEMM: C[m][n] = sum_k A[m][k]*B[n][k] (both K-major) -------
// MODE 0: fp16 out into PERMUTED GI layout (round-4 layout, verified):
//   col g: q=g>>8, jr=g&255; idx = ((((t*3+q)*32 + (jr>>5)*4 + ((jr>>2)&3))*NBP
//          + b)*8 + ((jr>>4)&1)*4 + (jr&3).  bias1[g] (+bias2[g] for g<512).
// MODE 1: fp32 partials out[(z*512+row)*N+col].  grid (M/128, N/128, splits)
template<int MODE>
__global__ __launch_bounds__(256, 2)
void gemm_bt(const f16* __restrict__ A, const f16* __restrict__ B,
             f16* __restrict__ Cb, float* __restrict__ Cf,
             const float* __restrict__ bias1, const float* __restrict__ bias2,
             int K, int N, int klen)
{
  const int l  = threadIdx.x & 63;
  const int w  = threadIdx.x >> 6;
  const int lr = l & 15, lg = l >> 4;
  const int Mb = blockIdx.x * 128 + (w >> 1) * 64;
  const int Nb = blockIdx.y * 128 + (w & 1) * 64;
  const int kb = blockIdx.z * klen;

  const f16* Ap = A + (size_t)(Mb + lr) * K + kb + lg * 8;
  const f16* Bp = B + (size_t)(Nb + lr) * K + kb + lg * 8;

  f32x4 acc[4][4];
  #pragma unroll
  for (int i = 0; i < 4; ++i)
    #pragma unroll
    for (int j = 0; j < 4; ++j)
      acc[i][j] = (f32x4){0.f, 0.f, 0.f, 0.f};

  for (int k = 0; k < klen; k += 32){
    f16x8 af[4], bfr[4];
    #pragma unroll
    for (int i = 0; i < 4; ++i){
      af[i]  = *(const f16x8*)(Ap + (size_t)i * 16 * K + k);
      bfr[i] = *(const f16x8*)(Bp + (size_t)i * 16 * K + k);
    }
    #pragma unroll
    for (int i = 0; i < 4; ++i)
      #pragma unroll
      for (int j = 0; j < 4; ++j)
        acc[i][j] = mfma16(af[i], bfr[j], acc[i][j]);
  }

  if (MODE == 0){
    float bv[4];
    #pragma unroll
    for (int j = 0; j < 4; ++j){
      int g = Nb + j*16 + lr;
      bv[j] = bias1[g] + (g < 512 ? bias2[g] : 0.f);
    }
    #pragma unroll
    for (int i = 0; i < 4; ++i)
      #pragma unroll
      for (int r = 0; r < 4; ++r){
        int row = Mb + i*16 + lg*4 + r;
        int t = (int)(((uint64_t)(uint32_t)row * 167773u) >> 25);  // row/200 exact
        int b = row - t*200;
        #pragma unroll
        for (int j = 0; j < 4; ++j){
          int g = Nb + j*16 + lr;
          int q = g >> 8, jr = g & 255;
          size_t idx = ((((size_t)t*3 + q)*32 + ((jr>>5)*4 + ((jr>>2)&3)))*NBP + b)*8
                       + ((jr>>4)&1)*4 + (jr&3);
          Cb[idx] = (f16)(acc[i][j][r] + bv[j]);
        }
      }
  } else {
    #pragma unroll
    for (int i = 0; i < 4; ++i)
      #pragma unroll
      for (int j = 0; j < 4; ++j)
        #pragma unroll
        for (int r = 0; r < 4; ++r){
          int row = Mb + i*16 + lg*4 + r;
          int col = Nb + j*16 + lr;
          Cf[((size_t)blockIdx.z * 512 + row) * N + col] = acc[i][j][r];
        }
  }
}

// ---------------- persistent GRU layer: 13 blocks x 16 batch rows ------------
// 512 threads = 8 waves = 2/SIMD; waves_per_eu(2,2) -> 128-VGPR budget (proven
// rounds 3-4). Wave w owns hidden [32w,32w+32) = 6 gate tiles. Weight bytes
// split 3 ways so the budget suffices AND latency is hidden (round-10 lesson):
//   3 tiles PINNED in regs (48 VGPR, opaque-asm pins hold within budget),
//   1 tile LDS-resident (8 waves x 8KB = 64KB, staged once, lane-linear),
//   2 tiles streamed from L2/step (128KB/block/step vs round 4's 384KB that
//   sat on the per-CU L2 port). gi single-buffered (wave-private chunks: read
//   then re-DMA own slices only). h dbuf in LDS (swizzle c(b)=(b^(b>>2))&3);
//   h_old in regs.
__global__ __launch_bounds__(512, 2)
__attribute__((amdgpu_waves_per_eu(2, 2)))
void gru_layer(const f16* __restrict__ whh, const float* __restrict__ bhh,
               const f16* __restrict__ gi, f16* __restrict__ hs)
{
  __shared__ __align__(16) unsigned char sm[106496];
  const int tid = threadIdx.x;
  const int w  = tid >> 6, l = tid & 63;
  const int lr = l & 15, lg = l >> 4;
  const int b0 = blockIdx.x * BW;
  const bool bval = (b0 + lr) < NB;

  ((int4*)(sm + HB))[tid] = make_int4(0,0,0,0);   // zero h buf0 (512*16B)

  // gi DMA: per-lane global src; LDS dest = wave-uniform chunk base + lane*16
  const f16* glane = gi + ((size_t)((w*4 + lg)*NBP + b0 + lr))*8;
#define DMA_GI() do { \
    _Pragma("unroll") \
    for (int Q = 0; Q < 3; ++Q) \
      __builtin_amdgcn_global_load_lds( \
          (const __attribute__((address_space(1))) void*)(glane + Q*(32*NBP*8)), \
          (__attribute__((address_space(3))) void*)(sm + GIB + Q*8192 + w*1024), \
          16, 0, 0); \
  } while(0)

  DMA_GI();   // t=0 prefetch

  // LDS-resident tile (q=1,t2=1): rows 256 + w*32 + 16 + [0,16)
  #pragma unroll
  for (int kk = 0; kk < 8; ++kk){
    f16x8 v = *(const f16x8*)(whh + (size_t)(256 + w*32 + 16 + lr)*256 + kk*32 + lg*8);
    *(f16x8*)(sm + w*8192 + kk*1024 + l*16) = v;
  }

  // pinned tiles (q,t2) = (0,0),(0,1),(1,0)
  f16x8 wR[3][8];
  {
    const int PQ[3] = {0,0,1}, PT[3] = {0,1,0};
    #pragma unroll
    for (int p = 0; p < 3; ++p)
      #pragma unroll
      for (int kk = 0; kk < 8; ++kk)
        wR[p][kk] = *(const f16x8*)(whh + (size_t)(PQ[p]*256 + w*32 + PT[p]*16 + lr)*256 + kk*32 + lg*8);
  }
  #pragma unroll
  for (int p = 0; p < 3; ++p)
    #pragma unroll
    for (int kk = 0; kk < 8; ++kk)
      asm volatile("" : "+v"(wR[p][kk]));   // 48 regs <= budget -> pins hold

  // streamed tiles (2,0),(2,1): n-gate
  const f16* wS0 = whh + (size_t)(512 + w*32 +  0 + lr)*256 + lg*8;
  const f16* wS1 = whh + (size_t)(512 + w*32 + 16 + lr)*256 + lg*8;

  // n-gate bias, packed f16
  f16x4 bn[2];
  #pragma unroll
  for (int t2 = 0; t2 < 2; ++t2){
    float4 bv = *(const float4*)(bhh + 512 + w*32 + t2*16 + lg*4);
    bn[t2] = (f16x4){(f16)bv.x,(f16)bv.y,(f16)bv.z,(f16)bv.w};
  }

  // LDS addressing. h element (k,b) at byte HB + P*8192 + (k>>5)*1024 + b*64 +
  //   (((k&31)*2) ^ (c(b)<<4)),  c(b) = (b ^ (b>>2)) & 3
  const int cswz = ((lr ^ (lr >> 2)) & 3) << 4;
  const int hrd = HB + lr*64 + ((lg*16) ^ cswz);           // + P*8192 + kk*1024
  const int hw0 = HB + w*1024 + lr*64 + ((lg*8) ^ cswz);   // + (P^1)*8192
  const int hw1 = hw0 ^ 32;
  const int gird = GIB + w*1024 + l*16;                    // + Q*8192

  f16* hp = hs + (size_t)(b0 + lr)*HD + w*32 + lg*4;
  f16x4 hvp0 = (f16x4){(f16)0.f,(f16)0.f,(f16)0.f,(f16)0.f};
  f16x4 hvp1 = hvp0;

  asm volatile("s_waitcnt vmcnt(0)" ::: "memory");  // drain prologue
  __syncthreads();

#define GRUSTEP(P) do { \
    f32x4 a00={0.f,0.f,0.f,0.f}, a01={0.f,0.f,0.f,0.f}, a10={0.f,0.f,0.f,0.f}; \
    f32x4 a11={0.f,0.f,0.f,0.f}, a20={0.f,0.f,0.f,0.f}, a21={0.f,0.f,0.f,0.f}; \
    _Pragma("unroll") \
    for (int kk = 0; kk < 8; ++kk){ \
      f16x8 hf = *(const f16x8*)(sm + (P)*8192 + kk*1024 + hrd); \
      f16x8 lw = *(const f16x8*)(sm + w*8192 + kk*1024 + l*16); \
      f16x8 s0 = *(const f16x8*)(wS0 + kk*32); \
      f16x8 s1 = *(const f16x8*)(wS1 + kk*32); \
      a00 = mfma16(wR[0][kk], hf, a00); \
      a01 = mfma16(wR[1][kk], hf, a01); \
      a10 = mfma16(wR[2][kk], hf, a10); \
      a11 = mfma16(lw, hf, a11); \
      a20 = mfma16(s0, hf, a20); \
      a21 = mfma16(s1, hf, a21); \
    } \
    asm volatile("s_waitcnt vmcnt(0)" ::: "memory"); /* prev-step gi DMAs done */ \
    f16x8 g0 = *(const f16x8*)(sm + gird + 0*8192); \
    f16x8 g1 = *(const f16x8*)(sm + gird + 1*8192); \
    f16x8 g2 = *(const f16x8*)(sm + gird + 2*8192); \
    f16x4 hv0, hv1; \
    _Pragma("unroll") \
    for (int r = 0; r < 4; ++r){ \
      float rg = __builtin_amdgcn_rcpf(1.f + __builtin_amdgcn_exp2f(-LOG2E*((float)g0[r] + a00[r]))); \
      float zg = __builtin_amdgcn_rcpf(1.f + __builtin_amdgcn_exp2f(-LOG2E*((float)g1[r] + a10[r]))); \
      float hn = a20[r] + (float)bn[0][r]; \
      float aa = (float)g2[r] + rg*hn; \
      float ng = 2.f*__builtin_amdgcn_rcpf(1.f + __builtin_amdgcn_exp2f(-2.f*LOG2E*aa)) - 1.f; \
      float h  = ng + zg*((float)hvp0[r] - ng); \
      hv0[r] = (f16)h; \
    } \
    _Pragma("unroll") \
    for (int r = 0; r < 4; ++r){ \
      float rg = __builtin_amdgcn_rcpf(1.f + __builtin_amdgcn_exp2f(-LOG2E*((float)g0[4+r] + a01[r]))); \
      float zg = __builtin_amdgcn_rcpf(1.f + __builtin_amdgcn_exp2f(-LOG2E*((float)g1[4+r] + a11[r]))); \
      float hn = a21[r] + (float)bn[1][r]; \
      float aa = (float)g2[4+r] + rg*hn; \
      float ng = 2.f*__builtin_amdgcn_rcpf(1.f + __builtin_amdgcn_exp2f(-2.f*LOG2E*aa)) - 1.f; \
      float h  = ng + zg*((float)hvp1[r] - ng); \
      hv1[r] = (f16)h; \
    } \
    hvp0 = hv0; hvp1 = hv1; \
    *(f16x4*)(sm + ((P)^1)*8192 + hw0) = hv0; \
    *(f16x4*)(sm + ((P)^1)*8192 + hw1) = hv1; \
    if (bval){ \
      *(f16x4*)(hp)      = hv0; \
      *(f16x4*)(hp + 16) = hv1; \
    } \
    hp += (size_t)NB*HD; \
    glane += GI_TSTRIDE; \
    DMA_GI();  /* next step, single buffer: issued AFTER this step's gi reads */ \
    asm volatile("s_waitcnt lgkmcnt(0)" ::: "memory"); \
    __builtin_amdgcn_sched_barrier(0); \
    __builtin_amdgcn_s_barrier(); \
    __builtin_amdgcn_sched_barrier(0); \
  } while(0)

  for (int th = 0; th < SEQ/2; ++th){
    GRUSTEP(0);
    GRUSTEP(1);
  }
#undef GRUSTEP
#undef DMA_GI
}

// ---------------- LayerNorm(hidden) + ReLU, in place on fp16 [rows][256] -----
__global__ __launch_bounds__(256)
void ln_relu(f16* __restrict__ hs, const float* __restrict__ lnw,
             const float* __restrict__ lnb)
{
  const int tid = threadIdx.x;
  const int wv = tid >> 6;           // 4 waves/block
  const int lane = tid & 63;
  const int half = lane >> 5;        // row within pair
  const int c0 = (lane & 31) * 8;
  float gw[8], gb[8];
  #pragma unroll
  for (int r = 0; r < 8; ++r){ gw[r] = lnw[c0 + r]; gb[r] = lnb[c0 + r]; }
  const int npairs = SEQ * NB / 2;   // 51200
  for (int pair = blockIdx.x * 4 + wv; pair < npairs; pair += gridDim.x * 4){
    f16* p = hs + (size_t)(pair*2 + half) * HD + c0;
    f16x8 v = *(const f16x8*)p;
    float f[8], s = 0.f, q = 0.f;
    #pragma unroll
    for (int r = 0; r < 8; ++r){ f[r] = (float)v[r]; s += f[r]; q += f[r]*f[r]; }
    #pragma unroll
    for (int off = 16; off; off >>= 1){
      s += __shfl_xor(s, off);
      q += __shfl_xor(q, off);
    }
    float mu = s * (1.f / HD);
    float var = q * (1.f / HD) - mu * mu;
    float rs = rsqrtf(var + 1e-5f);
    f16x8 o;
    #pragma unroll
    for (int r = 0; r < 8; ++r){
      float y = (f[r] - mu) * rs * gw[r] + gb[r];
      o[r] = (f16)fmaxf(y, 0.f);
    }
    *(f16x8*)p = o;
  }
}

// ---------------- BatchNorm over axis0 (batch stats) + ReLU ------------------
__global__ __launch_bounds__(512)
void bn_relu(const float* __restrict__ part, const float* __restrict__ g,
             const float* __restrict__ b, float* __restrict__ z)
{
  __shared__ float lds[16];
  const int o = blockIdx.x, s = threadIdx.x, w = s >> 6;
  float y = 0.f;
  #pragma unroll
  for (int p = 0; p < 8; ++p) y += part[((size_t)p * 512 + o) * 512 + s];
  float su = y, q = y * y;
  #pragma unroll
  for (int off = 32; off; off >>= 1){
    su += __shfl_down(su, off);
    q  += __shfl_down(q, off);
  }
  if ((s & 63) == 0){ lds[w] = su; lds[8 + w] = q; }
  __syncthreads();
  float S = 0.f, Q = 0.f;
  #pragma unroll
  for (int i = 0; i < 8; ++i){ S += lds[i]; Q += lds[8 + i]; }
  float mu = S * (1.f / 512.f);
  float var = Q * (1.f / 512.f) - mu * mu;
  float zz = fmaxf((y - mu) * rsqrtf(var + 1e-5f) * g[o] + b[o], 0.f);
  z[(size_t)o * 512 + s] = zz;   // stored transposed [o][s]
}

// ---------------- fc3: out[s][c] = sum_o z[o][s]*w[c][o] + b[c] --------------
__global__ __launch_bounds__(256)
void fc3_k(const float* __restrict__ z, const float* __restrict__ w,
           const float* __restrict__ b, float* __restrict__ out)
{
  __shared__ float lds[12];
  const int s = blockIdx.x, tid = threadIdx.x, wv = tid >> 6;
  float a0 = 0.f, a1 = 0.f, a2 = 0.f;
  for (int o = tid; o < 512; o += 256){
    float zz = z[(size_t)o * 512 + s];
    a0 += zz * w[o];
    a1 += zz * w[512 + o];
    a2 += zz * w[1024 + o];
  }
  #pragma unroll
  for (int off = 32; off; off >>= 1){
    a0 += __shfl_down(a0, off);
    a1 += __shfl_down(a1, off);
    a2 += __shfl_down(a2, off);
  }
  if ((tid & 63) == 0){ lds[wv] = a0; lds[4 + wv] = a1; lds[8 + wv] = a2; }
  __syncthreads();
  if (tid == 0){
    out[s*3 + 0] = lds[0] + lds[1] + lds[2]  + lds[3]  + b[0];
    out[s*3 + 1] = lds[4] + lds[5] + lds[6]  + lds[7]  + b[1];
    out[s*3 + 2] = lds[8] + lds[9] + lds[10] + lds[11] + b[2];
  }
}

extern "C" void kernel_launch(void* const* d_in, const int* in_sizes, int n_in,
                              void* d_out, int out_size, void* d_ws, size_t ws_size,
                              hipStream_t stream)
{
  (void)in_sizes; (void)n_in; (void)out_size; (void)ws_size;
  const float* x    = (const float*)d_in[0];
  const float* wih0 = (const float*)d_in[1];
  const float* whh0 = (const float*)d_in[2];
  const float* bih0 = (const float*)d_in[3];
  const float* bhh0 = (const float*)d_in[4];
  const float* wih1 = (const float*)d_in[5];
  const float* whh1 = (const float*)d_in[6];
  const float* bih1 = (const float*)d_in[7];
  const float* bhh1 = (const float*)d_in[8];
  const float* lnw  = (const float*)d_in[9];
  const float* lnb  = (const float*)d_in[10];
  const float* fc2w = (const float*)d_in[11];
  // d_in[12] = fc2_b skipped: BN mean-centering cancels constant column bias.
  const float* bng  = (const float*)d_in[13];
  const float* bnb  = (const float*)d_in[14];
  const float* fc3w = (const float*)d_in[15];
  const float* fc3b = (const float*)d_in[16];
  float* out = (float*)d_out;

  char* ws = (char*)d_ws;
  size_t off = 0;
  auto alloc = [&](size_t bytes) -> void* {
    void* p = ws + off; off += (bytes + 255) & ~(size_t)255; return p;
  };
  f16* GI     = (f16*)alloc((size_t)(SEQ+1)*GI_TSTRIDE*2); // 163.9 MB (+1 step: last prefetch reads in-bounds)
  f16* X16    = (f16*)alloc((size_t)SEQ*NB*64*2);       // 13.1 MB
  f16* WI0    = (f16*)alloc((size_t)768*64*2);
  f16* WH0    = (f16*)alloc((size_t)768*256*2);
  f16* WI1    = (f16*)alloc((size_t)768*256*2);
  f16* WH1    = (f16*)alloc((size_t)768*256*2);
  f16* HS0    = (f16*)alloc((size_t)SEQ*NB*256*2);      // 52.4 MB
  f16* HS1    = (f16*)alloc((size_t)SEQ*NB*256*2);      // 52.4 MB
  float* PART = (float*)alloc((size_t)8*512*512*4);     // 8.4 MB
  float* Z    = (float*)alloc((size_t)512*512*4);       // 1 MB (total ~292 MB)
  f16* FC2W   = GI;   // aliased: GI dead after gru1, FC2W converted after gru1

  cvt_f32_f16<<<2048,256,0,stream>>>(x,    X16,  SEQ*NB*64/4);
  cvt_f32_f16<<<64,  256,0,stream>>>(wih0, WI0,  768*64/4);
  cvt_f32_f16<<<192, 256,0,stream>>>(whh0, WH0,  768*256/4);
  cvt_f32_f16<<<192, 256,0,stream>>>(wih1, WI1,  768*256/4);
  cvt_f32_f16<<<192, 256,0,stream>>>(whh1, WH1,  768*256/4);

  dim3 g0(800, 6, 1);
  // gi0 = x @ w_ih0^T + b_ih0 (+ b_hh0 for r,z gates), permuted layout
  gemm_bt<0><<<g0, 256, 0, stream>>>(X16, WI0, GI, nullptr, bih0, bhh0, 64, GD, 64);
  gru_layer<<<NBLK, 512, 0, stream>>>(WH0, bhh0, GI, HS0);
  gemm_bt<0><<<g0, 256, 0, stream>>>(HS0, WI1, GI, nullptr, bih1, bhh1, 256, GD, 256);
  gru_layer<<<NBLK, 512, 0, stream>>>(WH1, bhh1, GI, HS1);
  // LayerNorm + ReLU in place -> hflat (fp16, layout already (512, 51200))
  ln_relu<<<3200, 256, 0, stream>>>(HS1, lnw, lnb);
  // fc2 weights converted now (GI dead), into GI-aliased buffer
  cvt_f32_f16<<<4096,256,0,stream>>>(fc2w, FC2W, 512*51200/4);
  dim3 g2(4, 4, 8);
  gemm_bt<1><<<g2, 256, 0, stream>>>(FC2W, HS1, nullptr, PART, nullptr, nullptr, 51200, 512, 6400);
  bn_relu<<<512, 512, 0, stream>>>(PART, bng, bnb, Z);
  fc3_k<<<512, 256, 0, stream>>>(Z, fc3w, fc3b, out);
}

// Round 12
// 3269.238 us; speedup vs baseline: 2.2570x; 1.4741x over previous
//
#include <hip/hip_runtime.h>
#include <stdint.h>

typedef _Float16 f16;
typedef _Float16 f16x4 __attribute__((ext_vector_type(4)));
typedef _Float16 f16x8 __attribute__((ext_vector_type(8)));
typedef float f32x4 __attribute__((ext_vector_type(4)));

#define SEQ 512
#define NB  200
#define HD  256
#define GD  768
#define BW  16
#define NBLK 13                 // ceil(200/16)
#define GI_TSTRIDE (NB*GD)      // halves per timestep = 153600 (row-major)
#define LOG2E 1.44269504f

__device__ __forceinline__ f32x4 mfma16(f16x8 a, f16x8 b, f32x4 c){
  return __builtin_amdgcn_mfma_f32_16x16x32_f16(a, b, c, 0, 0, 0);
}

// ---------------- fp32 -> fp16 convert ----------------
__global__ void cvt_f32_f16(const float* __restrict__ src, f16* __restrict__ dst, int n4){
  int i = blockIdx.x * blockDim.x + threadIdx.x;
  int stride = gridDim.x * blockDim.x;
  for (; i < n4; i += stride){
    float4 v = ((const float4*)src)[i];
    f16x4 o = { (f16)v.x, (f16)v.y, (f16)v.z, (f16)v.w };
    ((f16x4*)dst)[i] = o;
  }
}

// ---------------- GEMM: C[m][n] = sum_k A[m][k]*B[n][k] (both K-major) -------
// MODE 0: fp16 out, ROW-MAJOR [row][768] with intra-32-col permutation
//   g' = (g & ~31) | ((g>>2)&3)*8 + ((g>>4)&1)*4 + (g&3)
//   (matches the MFMA D-layout so each gru lane's 8 gate values are one
//   contiguous 16B slice). Writes land within 64-128B windows per row ->
//   near-coalesced, vs the old 4KB-scattered 2B stores.
//   bias1[g] (+bias2[g] for g<512: b_hh r,z folded in exactly).
// MODE 1: fp32 partials out[(z*512+row)*N+col].  grid (M/128, N/128, splits)
template<int MODE>
__global__ __launch_bounds__(256, 2)
void gemm_bt(const f16* __restrict__ A, const f16* __restrict__ B,
             f16* __restrict__ Cb, float* __restrict__ Cf,
             const float* __restrict__ bias1, const float* __restrict__ bias2,
             int K, int N, int klen)
{
  const int l  = threadIdx.x & 63;
  const int w  = threadIdx.x >> 6;
  const int lr = l & 15, lg = l >> 4;
  const int Mb = blockIdx.x * 128 + (w >> 1) * 64;
  const int Nb = blockIdx.y * 128 + (w & 1) * 64;
  const int kb = blockIdx.z * klen;

  const f16* Ap = A + (size_t)(Mb + lr) * K + kb + lg * 8;
  const f16* Bp = B + (size_t)(Nb + lr) * K + kb + lg * 8;

  f32x4 acc[4][4];
  #pragma unroll
  for (int i = 0; i < 4; ++i)
    #pragma unroll
    for (int j = 0; j < 4; ++j)
      acc[i][j] = (f32x4){0.f, 0.f, 0.f, 0.f};

  for (int k = 0; k < klen; k += 32){
    f16x8 af[4], bfr[4];
    #pragma unroll
    for (int i = 0; i < 4; ++i){
      af[i]  = *(const f16x8*)(Ap + (size_t)i * 16 * K + k);
      bfr[i] = *(const f16x8*)(Bp + (size_t)i * 16 * K + k);
    }
    #pragma unroll
    for (int i = 0; i < 4; ++i)
      #pragma unroll
      for (int j = 0; j < 4; ++j)
        acc[i][j] = mfma16(af[i], bfr[j], acc[i][j]);
  }

  if (MODE == 0){
    float bv[4];
    int gc[4];
    #pragma unroll
    for (int j = 0; j < 4; ++j){
      int g = Nb + j*16 + lr;
      bv[j] = bias1[g] + (g < 512 ? bias2[g] : 0.f);
      int x = g & 31;
      gc[j] = (g & ~31) | (((x>>2)&3)*8 + ((x>>4)&1)*4 + (x&3));
    }
    #pragma unroll
    for (int i = 0; i < 4; ++i)
      #pragma unroll
      for (int r = 0; r < 4; ++r){
        size_t rowb = (size_t)(Mb + i*16 + lg*4 + r) * GD;
        #pragma unroll
        for (int j = 0; j < 4; ++j)
          Cb[rowb + gc[j]] = (f16)(acc[i][j][r] + bv[j]);
      }
  } else {
    #pragma unroll
    for (int i = 0; i < 4; ++i)
      #pragma unroll
      for (int j = 0; j < 4; ++j)
        #pragma unroll
        for (int r = 0; r < 4; ++r){
          int row = Mb + i*16 + lg*4 + r;
          int col = Nb + j*16 + lr;
          Cf[((size_t)blockIdx.z * 512 + row) * N + col] = acc[i][j][r];
        }
  }
}

// ---------------- persistent GRU layer: 13 blocks x 16 batch rows ------------
// ROUND-4 KERNEL VERBATIM (the measured optimum: 1073us, 1.05us/step —
// compiler-pipelined weight streaming from L2; every hand-managed register/
// LDS/AGPR variant of rounds 5-11 was equal or worse). Only the gi DMA source
// changed: permuted-row-major GI, lane (lg,lr) sources 16B at
// (t*200+b0+lr)*768 + q*256 + w*32 + lg*8.
__global__ __launch_bounds__(512, 2)
__attribute__((amdgpu_waves_per_eu(2, 2)))
void gru_layer(const f16* __restrict__ whh, const float* __restrict__ bhh,
               const f16* __restrict__ gi, f16* __restrict__ hs)
{
  // [0,16384): h bufs (2x8192). [16384,65536): gi bufs (2x24576). rest: pad
  // (keeps 1 block/CU).
  __shared__ __align__(16) unsigned char sm[16384 + 49152 + 24576];
  const int tid = threadIdx.x;
  const int w  = tid >> 6, l = tid & 63;
  const int lr = l & 15, lg = l >> 4;
  const int b0 = blockIdx.x * BW;
  const bool bval = (b0 + lr) < NB;

  ((int4*)sm)[tid] = make_int4(0,0,0,0);   // zero h buf0 (512*16B = 8192)
  ((int4*)(sm + 65536))[tid] = make_int4(0,0,0,0);  // touch pad

  // gi DMA: per-lane global src (16B, contiguous under the g' permutation);
  // LDS dest = wave-uniform chunk base + lane*16
  const f16* glane = gi + (size_t)(b0 + lr)*GD + w*32 + lg*8;
#define DMA_GI(P, Q) \
  __builtin_amdgcn_global_load_lds( \
      (const __attribute__((address_space(1))) void*)(glane + (Q)*256), \
      (__attribute__((address_space(3))) void*)(sm + 16384 + (P)*24576 + (Q)*8192 + w*1024), \
      16, 0, 0)

  DMA_GI(0,0); DMA_GI(0,1); DMA_GI(0,2);   // t=0 prefetch

  // weight fragments: tile (q,t2) covers gate rows q*256 + w*32 + t2*16 + [0,16)
  f16x8 wA[6][8];
  #pragma unroll
  for (int q = 0; q < 3; ++q)
    #pragma unroll
    for (int t2 = 0; t2 < 2; ++t2)
      #pragma unroll
      for (int kk = 0; kk < 8; ++kk)
        wA[q*2+t2][kk] = *(const f16x8*)(whh + (size_t)(q*256 + w*32 + t2*16 + lr)*256 + kk*32 + lg*8);

  #pragma unroll
  for (int i = 0; i < 6; ++i)
    #pragma unroll
    for (int kk = 0; kk < 8; ++kk)
      asm volatile("" : "+v"(wA[i][kk]));

  // n-gate bias, packed f16
  f16x4 bn[2];
  #pragma unroll
  for (int t2 = 0; t2 < 2; ++t2){
    float4 bv = *(const float4*)(bhh + 512 + w*32 + t2*16 + lg*4);
    bn[t2] = (f16x4){(f16)bv.x,(f16)bv.y,(f16)bv.z,(f16)bv.w};
  }

  // LDS addressing. h element (k,b) at byte:
  //   (k>>5)*1024 + b*64 + (((k&31)*2) ^ (c(b)<<4)),  c(b) = (b ^ (b>>2)) & 3
  const int cswz = ((lr ^ (lr >> 2)) & 3) << 4;
  const int hrd = lr*64 + ((lg*16) ^ cswz);           // + kk*1024 + P*8192
  const int hw0 = w*1024 + lr*64 + ((lg*8) ^ cswz);   // own h, t2=0
  const int hw1 = hw0 ^ 32;                           // own h, t2=1
  const int gird = 16384 + w*1024 + l*16;             // + q*8192 + P*24576

  f16* hp = hs + (size_t)(b0 + lr)*HD + w*32 + lg*4;
  f16x4 hvp0 = (f16x4){(f16)0.f,(f16)0.f,(f16)0.f,(f16)0.f};
  f16x4 hvp1 = hvp0;

  asm volatile("s_waitcnt vmcnt(0)" ::: "memory");  // drain prologue
  __syncthreads();

#define GRUSTEP(P) do { \
    f32x4 a00={0.f,0.f,0.f,0.f}, a01={0.f,0.f,0.f,0.f}, a10={0.f,0.f,0.f,0.f}; \
    f32x4 a11={0.f,0.f,0.f,0.f}, a20={0.f,0.f,0.f,0.f}, a21={0.f,0.f,0.f,0.f}; \
    _Pragma("unroll") \
    for (int kk = 0; kk < 8; ++kk){ \
      f16x8 hf = *(const f16x8*)(sm + (P)*8192 + kk*1024 + hrd); \
      a00 = mfma16(wA[0][kk], hf, a00); \
      a01 = mfma16(wA[1][kk], hf, a01); \
      a10 = mfma16(wA[2][kk], hf, a10); \
      a11 = mfma16(wA[3][kk], hf, a11); \
      a20 = mfma16(wA[4][kk], hf, a20); \
      a21 = mfma16(wA[5][kk], hf, a21); \
    } \
    asm volatile("s_waitcnt vmcnt(2)" ::: "memory"); /* 3 gi DMAs done */ \
    f16x8 g0 = *(const f16x8*)(sm + (P)*24576 + 0*8192 + gird); \
    f16x8 g1 = *(const f16x8*)(sm + (P)*24576 + 1*8192 + gird); \
    f16x8 g2 = *(const f16x8*)(sm + (P)*24576 + 2*8192 + gird); \
    glane += GI_TSTRIDE; \
    DMA_GI((P)^1, 0); DMA_GI((P)^1, 1); DMA_GI((P)^1, 2); \
    f16x4 hv0, hv1; \
    _Pragma("unroll") \
    for (int r = 0; r < 4; ++r){ \
      float rg = __builtin_amdgcn_rcpf(1.f + __builtin_amdgcn_exp2f(-LOG2E*((float)g0[r] + a00[r]))); \
      float zg = __builtin_amdgcn_rcpf(1.f + __builtin_amdgcn_exp2f(-LOG2E*((float)g1[r] + a10[r]))); \
      float hn = a20[r] + (float)bn[0][r]; \
      float aa = (float)g2[r] + rg*hn; \
      float ng = 2.f*__builtin_amdgcn_rcpf(1.f + __builtin_amdgcn_exp2f(-2.f*LOG2E*aa)) - 1.f; \
      float h  = ng + zg*((float)hvp0[r] - ng); \
      hv0[r] = (f16)h; \
    } \
    _Pragma("unroll") \
    for (int r = 0; r < 4; ++r){ \
      float rg = __builtin_amdgcn_rcpf(1.f + __builtin_amdgcn_exp2f(-LOG2E*((float)g0[4+r] + a01[r]))); \
      float zg = __builtin_amdgcn_rcpf(1.f + __builtin_amdgcn_exp2f(-LOG2E*((float)g1[4+r] + a11[r]))); \
      float hn = a21[r] + (float)bn[1][r]; \
      float aa = (float)g2[4+r] + rg*hn; \
      float ng = 2.f*__builtin_amdgcn_rcpf(1.f + __builtin_amdgcn_exp2f(-2.f*LOG2E*aa)) - 1.f; \
      float h  = ng + zg*((float)hvp1[r] - ng); \
      hv1[r] = (f16)h; \
    } \
    hvp0 = hv0; hvp1 = hv1; \
    *(f16x4*)(sm + ((P)^1)*8192 + hw0) = hv0; \
    *(f16x4*)(sm + ((P)^1)*8192 + hw1) = hv1; \
    if (bval){ \
      *(f16x4*)(hp)      = hv0; \
      *(f16x4*)(hp + 16) = hv1; \
    } \
    hp += (size_t)NB*HD; \
    asm volatile("s_waitcnt lgkmcnt(0)" ::: "memory"); \
    __builtin_amdgcn_sched_barrier(0); \
    __builtin_amdgcn_s_barrier(); \
    __builtin_amdgcn_sched_barrier(0); \
  } while(0)

  for (int th = 0; th < SEQ/2; ++th){
    GRUSTEP(0);
    GRUSTEP(1);
  }
#undef GRUSTEP
#undef DMA_GI
}

// ---------------- LayerNorm(hidden) + ReLU, in place on fp16 [rows][256] -----
__global__ __launch_bounds__(256)
void ln_relu(f16* __restrict__ hs, const float* __restrict__ lnw,
             const float* __restrict__ lnb)
{
  const int tid = threadIdx.x;
  const int wv = tid >> 6;           // 4 waves/block
  const int lane = tid & 63;
  const int half = lane >> 5;        // row within pair
  const int c0 = (lane & 31) * 8;
  float gw[8], gb[8];
  #pragma unroll
  for (int r = 0; r < 8; ++r){ gw[r] = lnw[c0 + r]; gb[r] = lnb[c0 + r]; }
  const int npairs = SEQ * NB / 2;   // 51200
  for (int pair = blockIdx.x * 4 + wv; pair < npairs; pair += gridDim.x * 4){
    f16* p = hs + (size_t)(pair*2 + half) * HD + c0;
    f16x8 v = *(const f16x8*)p;
    float f[8], s = 0.f, q = 0.f;
    #pragma unroll
    for (int r = 0; r < 8; ++r){ f[r] = (float)v[r]; s += f[r]; q += f[r]*f[r]; }
    #pragma unroll
    for (int off = 16; off; off >>= 1){
      s += __shfl_xor(s, off);
      q += __shfl_xor(q, off);
    }
    float mu = s * (1.f / HD);
    float var = q * (1.f / HD) - mu * mu;
    float rs = rsqrtf(var + 1e-5f);
    f16x8 o;
    #pragma unroll
    for (int r = 0; r < 8; ++r){
      float y = (f[r] - mu) * rs * gw[r] + gb[r];
      o[r] = (f16)fmaxf(y, 0.f);
    }
    *(f16x8*)p = o;
  }
}

// ---------------- BatchNorm over axis0 (batch stats) + ReLU ------------------
__global__ __launch_bounds__(512)
void bn_relu(const float* __restrict__ part, const float* __restrict__ g,
             const float* __restrict__ b, float* __restrict__ z)
{
  __shared__ float lds[16];
  const int o = blockIdx.x, s = threadIdx.x, w = s >> 6;
  float y = 0.f;
  #pragma unroll
  for (int p = 0; p < 8; ++p) y += part[((size_t)p * 512 + o) * 512 + s];
  float su = y, q = y * y;
  #pragma unroll
  for (int off = 32; off; off >>= 1){
    su += __shfl_down(su, off);
    q  += __shfl_down(q, off);
  }
  if ((s & 63) == 0){ lds[w] = su; lds[8 + w] = q; }
  __syncthreads();
  float S = 0.f, Q = 0.f;
  #pragma unroll
  for (int i = 0; i < 8; ++i){ S += lds[i]; Q += lds[8 + i]; }
  float mu = S * (1.f / 512.f);
  float var = Q * (1.f / 512.f) - mu * mu;
  float zz = fmaxf((y - mu) * rsqrtf(var + 1e-5f) * g[o] + b[o], 0.f);
  z[(size_t)o * 512 + s] = zz;   // stored transposed [o][s]
}

// ---------------- fc3: out[s][c] = sum_o z[o][s]*w[c][o] + b[c] --------------
__global__ __launch_bounds__(256)
void fc3_k(const float* __restrict__ z, const float* __restrict__ w,
           const float* __restrict__ b, float* __restrict__ out)
{
  __shared__ float lds[12];
  const int s = blockIdx.x, tid = threadIdx.x, wv = tid >> 6;
  float a0 = 0.f, a1 = 0.f, a2 = 0.f;
  for (int o = tid; o < 512; o += 256){
    float zz = z[(size_t)o * 512 + s];
    a0 += zz * w[o];
    a1 += zz * w[512 + o];
    a2 += zz * w[1024 + o];
  }
  #pragma unroll
  for (int off = 32; off; off >>= 1){
    a0 += __shfl_down(a0, off);
    a1 += __shfl_down(a1, off);
    a2 += __shfl_down(a2, off);
  }
  if ((tid & 63) == 0){ lds[wv] = a0; lds[4 + wv] = a1; lds[8 + wv] = a2; }
  __syncthreads();
  if (tid == 0){
    out[s*3 + 0] = lds[0] + lds[1] + lds[2]  + lds[3]  + b[0];
    out[s*3 + 1] = lds[4] + lds[5] + lds[6]  + lds[7]  + b[1];
    out[s*3 + 2] = lds[8] + lds[9] + lds[10] + lds[11] + b[2];
  }
}

extern "C" void kernel_launch(void* const* d_in, const int* in_sizes, int n_in,
                              void* d_out, int out_size, void* d_ws, size_t ws_size,
                              hipStream_t stream)
{
  (void)in_sizes; (void)n_in; (void)out_size; (void)ws_size;
  const float* x    = (const float*)d_in[0];
  const float* wih0 = (const float*)d_in[1];
  const float* whh0 = (const float*)d_in[2];
  const float* bih0 = (const float*)d_in[3];
  const float* bhh0 = (const float*)d_in[4];
  const float* wih1 = (const float*)d_in[5];
  const float* whh1 = (const float*)d_in[6];
  const float* bih1 = (const float*)d_in[7];
  const float* bhh1 = (const float*)d_in[8];
  const float* lnw  = (const float*)d_in[9];
  const float* lnb  = (const float*)d_in[10];
  const float* fc2w = (const float*)d_in[11];
  // d_in[12] = fc2_b skipped: BN mean-centering cancels constant column bias.
  const float* bng  = (const float*)d_in[13];
  const float* bnb  = (const float*)d_in[14];
  const float* fc3w = (const float*)d_in[15];
  const float* fc3b = (const float*)d_in[16];
  float* out = (float*)d_out;

  char* ws = (char*)d_ws;
  size_t off = 0;
  auto alloc = [&](size_t bytes) -> void* {
    void* p = ws + off; off += (bytes + 255) & ~(size_t)255; return p;
  };
  f16* GI     = (f16*)alloc((size_t)(SEQ+1)*NB*GD*2);   // 157.6 MB (row-major, +1 step pad)
  f16* X16    = (f16*)alloc((size_t)SEQ*NB*64*2);       // 13.1 MB
  f16* WI0    = (f16*)alloc((size_t)768*64*2);
  f16* WH0    = (f16*)alloc((size_t)768*256*2);
  f16* WI1    = (f16*)alloc((size_t)768*256*2);
  f16* WH1    = (f16*)alloc((size_t)768*256*2);
  f16* HS0    = (f16*)alloc((size_t)SEQ*NB*256*2);      // 52.4 MB
  f16* HS1    = (f16*)alloc((size_t)SEQ*NB*256*2);      // 52.4 MB
  float* PART = (float*)alloc((size_t)8*512*512*4);     // 8.4 MB
  float* Z    = (float*)alloc((size_t)512*512*4);       // 1 MB (total ~286 MB)
  f16* FC2W   = GI;   // aliased: GI dead after gru1, FC2W converted after gru1

  cvt_f32_f16<<<2048,256,0,stream>>>(x,    X16,  SEQ*NB*64/4);
  cvt_f32_f16<<<64,  256,0,stream>>>(wih0, WI0,  768*64/4);
  cvt_f32_f16<<<192, 256,0,stream>>>(whh0, WH0,  768*256/4);
  cvt_f32_f16<<<192, 256,0,stream>>>(wih1, WI1,  768*256/4);
  cvt_f32_f16<<<192, 256,0,stream>>>(whh1, WH1,  768*256/4);

  dim3 g0(800, 6, 1);
  // gi0 = x @ w_ih0^T + b_ih0 (+ b_hh0 for r,z gates), permuted row-major
  gemm_bt<0><<<g0, 256, 0, stream>>>(X16, WI0, GI, nullptr, bih0, bhh0, 64, GD, 64);
  gru_layer<<<NBLK, 512, 0, stream>>>(WH0, bhh0, GI, HS0);
  gemm_bt<0><<<g0, 256, 0, stream>>>(HS0, WI1, GI, nullptr, bih1, bhh1, 256, GD, 256);
  gru_layer<<<NBLK, 512, 0, stream>>>(WH1, bhh1, GI, HS1);
  // LayerNorm + ReLU in place -> hflat (fp16, layout already (512, 51200))
  ln_relu<<<3200, 256, 0, stream>>>(HS1, lnw, lnb);
  // fc2 weights converted now (GI dead), into GI-aliased buffer
  cvt_f32_f16<<<4096,256,0,stream>>>(fc2w, FC2W, 512*51200/4);
  dim3 g2(4, 4, 8);
  gemm_bt<1><<<g2, 256, 0, stream>>>(FC2W, HS1, nullptr, PART, nullptr, nullptr, 51200, 512, 6400);
  bn_relu<<<512, 512, 0, stream>>>(PART, bng, bnb, Z);
  fc3_k<<<512, 256, 0, stream>>>(Z, fc3w, fc3b, out);
}